// Round 3
// baseline (512.297 us; speedup 1.0000x reference)
//
#include <hip/hip_runtime.h>
#include <hip/hip_bf16.h>

// TemporalLinearAttention: out = ((softmax_d(q)*s) @ k_sm^T @ v) @ w_out
// qkv = x @ w_qkv, reassociated (q@k^T)@v.
// Pipeline: conv_x, conv_w -> gemm8<6,bf16> (qkv) -> attn -> gemm8<2,f32> (out)
//
// gemm8: 256x256 tile, BK=64, 512 thr (8 waves 2Mx4N), 8-phase K-loop,
// chunk-XOR LDS swizzle (c^=row&7, 16B granules), counted vmcnt(2) at ph4/ph8.
// Region-safety: phase = (M-half, K-half); A-halves of a buf last read ph4/ph8,
// B-halves ph3/ph7 -> stages of next tile into same buf issue strictly later.

typedef __attribute__((ext_vector_type(8))) short bf16x8;
typedef __attribute__((ext_vector_type(4))) float f32x4;

__device__ __forceinline__ unsigned short f2bf(float f) {
  __hip_bfloat16 h = __float2bfloat16(f);
  return __builtin_bit_cast(unsigned short, h);
}
__device__ __forceinline__ float bf2f(unsigned short u) {
  unsigned int v = ((unsigned int)u) << 16;
  return __builtin_bit_cast(float, v);
}
__device__ __forceinline__ void gload16(const void* g, void* l) {
  __builtin_amdgcn_global_load_lds(
      (__attribute__((address_space(1))) void*)g,
      (__attribute__((address_space(3))) void*)l, 16, 0, 0);
}

// ---------------- conversions ----------------
__global__ __launch_bounds__(256) void conv_x_k(const float* __restrict__ x,
                                                unsigned short* __restrict__ xb) {
  size_t i = ((size_t)blockIdx.x * 256 + threadIdx.x) * 8;
  float4 a = *(const float4*)(x + i);
  float4 b = *(const float4*)(x + i + 4);
  union { unsigned short u[8]; bf16x8 v; } o;
  o.u[0] = f2bf(a.x); o.u[1] = f2bf(a.y); o.u[2] = f2bf(a.z); o.u[3] = f2bf(a.w);
  o.u[4] = f2bf(b.x); o.u[5] = f2bf(b.y); o.u[6] = f2bf(b.z); o.u[7] = f2bf(b.w);
  *(bf16x8*)(xb + i) = o.v;
}

__global__ __launch_bounds__(256) void conv_w_k(const float* __restrict__ wq,
                                                const float* __restrict__ wo,
                                                unsigned short* __restrict__ wqt,
                                                unsigned short* __restrict__ wot) {
  int i = blockIdx.x * 256 + threadIdx.x;
  if (i < 786432) {
    int n = i >> 9, k = i & 511;
    wqt[i] = f2bf(wq[k * 1536 + n]);
  } else {
    int j = i - 786432;
    int n = j >> 9, k = j & 511;
    wot[j] = f2bf(wo[k * 512 + n]);
  }
}

// ---------------- 8-phase 256x256 GEMM (K=512 fixed) ----------------
// LDS (ushort idx): A buf0 @0, A buf1 @16384, B buf0 @32768, B buf1 @49152.
// Tile layout per buf: [256 rows][8 chunks of 8 bf16], phys chunk = c ^ (row&7).
#define ABUF0 0
#define ABUF1 16384
#define BBUF0 32768
#define BBUF1 49152

// Stage one half-tile (128 rows x 64 k) = 2 gload16/thread. Linear LDS dest;
// global source pre-swizzled so phys chunk p holds logical chunk p^(row&7).
__device__ __forceinline__ void stage_half(const unsigned short* __restrict__ G,
                                           int grow0, unsigned short* ldsb,
                                           int tid, int kofs) {
  int r = tid >> 3;                      // row within half (0..63), +64 for 2nd
  int c = ((tid & 7) ^ (r & 7)) << 3;    // logical k-chunk for this phys slot
  gload16(G + (size_t)(grow0 + r) * 512 + kofs + c, ldsb + tid * 8);
  gload16(G + (size_t)(grow0 + 64 + r) * 512 + kofs + c, ldsb + 4096 + tid * 8);
}

#define RD_A(base, mh, sw)                                                   \
  _Pragma("unroll") for (int mf = 0; mf < 4; ++mf)                           \
      aF[mf] = *(const bf16x8*)&lds[(base) + (rowA + (mh)*64 + mf*16) * 64 + (sw)];
#define RD_B(base, sw)                                                       \
  _Pragma("unroll") for (int nf = 0; nf < 4; ++nf)                           \
      bF[nf] = *(const bf16x8*)&lds[(base) + (rowB + nf*16) * 64 + (sw)];
#define DO_MFMA(mh)                                                          \
  __builtin_amdgcn_s_setprio(1);                                             \
  _Pragma("unroll") for (int mf = 0; mf < 4; ++mf)                           \
  _Pragma("unroll") for (int nf = 0; nf < 4; ++nf)                           \
      acc[(mh)*4 + mf][nf] = __builtin_amdgcn_mfma_f32_16x16x32_bf16(        \
          aF[mf], bF[nf], acc[(mh)*4 + mf][nf], 0, 0, 0);                    \
  __builtin_amdgcn_s_setprio(0);
#define PBAR() __builtin_amdgcn_s_barrier()
#define LGKM0()                                          \
  do {                                                   \
    asm volatile("s_waitcnt lgkmcnt(0)" ::: "memory");   \
    __builtin_amdgcn_sched_barrier(0);                   \
  } while (0)
#define VM2() asm volatile("s_waitcnt vmcnt(2)" ::: "memory")

template <int NTN, bool OUTBF>
__global__ __launch_bounds__(512) void gemm8_k(const unsigned short* __restrict__ A,
                                               const unsigned short* __restrict__ B,
                                               void* __restrict__ Cv) {
  __shared__ __align__(16) unsigned short lds[65536];  // 128 KiB
  int orig = blockIdx.x;
  int id = (orig & 7) * (gridDim.x >> 3) + (orig >> 3);  // XCD-chunked (grid%8==0)
  int mt = id / NTN, nt = id % NTN;
  int m0 = mt * 256, n0 = nt * 256;
  int tid = threadIdx.x, wid = tid >> 6, l = tid & 63;
  int wr = wid >> 2, wc = wid & 3;          // 2M x 4N waves; wave owns 128x64
  int rowA = wr * 128 + (l & 15);
  int rowB = wc * 64 + (l & 15);
  int r7 = l & 7;
  int sw0 = ((l >> 4) ^ r7) << 3;           // swizzled chunk offset, ks=0
  int sw1 = (((l >> 4) | 4) ^ r7) << 3;     // ks=1

  f32x4 acc[8][4];
#pragma unroll
  for (int i = 0; i < 8; ++i)
#pragma unroll
    for (int j = 0; j < 4; ++j) acc[i][j] = (f32x4){0.f, 0.f, 0.f, 0.f};
  bf16x8 aF[4], bF[4];

  // Prologue: tile0 (4 halves) + tile1.Bh1; vmcnt(2) leaves only tile1.Bh1 in flight.
  stage_half(B, n0,       lds + BBUF0,        tid, 0);
  stage_half(B, n0 + 128, lds + BBUF0 + 8192, tid, 0);
  stage_half(A, m0,       lds + ABUF0,        tid, 0);
  stage_half(A, m0 + 128, lds + ABUF0 + 8192, tid, 0);
  stage_half(B, n0,       lds + BBUF1,        tid, 64);
  VM2();
  PBAR();

  for (int it = 0; it < 4; ++it) {
    int k1 = (2 * it + 1) * 64;
    int t2 = 2 * it + 2; if (t2 > 7) t2 = 7;   // tail: clamped stages hit dead regions
    int t3 = 2 * it + 3; if (t3 > 7) t3 = 7;
    int k2 = t2 * 64, k3 = t3 * 64;

    // ph1: buf0 (M0,ks0); stage tile(2i+1).Bh2 -> BBUF1.h2 (free since prev ph7)
    RD_A(ABUF0, 0, sw0); RD_B(BBUF0, sw0);
    stage_half(B, n0 + 128, lds + BBUF1 + 8192, tid, k1);
    PBAR(); LGKM0(); DO_MFMA(0); PBAR();
    // ph2: buf0 (M1,ks0); stage (2i+1).Ah1 (ABUF1 free since prev ph8)
    RD_A(ABUF0, 1, sw0);
    stage_half(A, m0, lds + ABUF1, tid, k1);
    PBAR(); LGKM0(); DO_MFMA(1); PBAR();
    // ph3: buf0 (M0,ks1); stage (2i+1).Ah2
    RD_A(ABUF0, 0, sw1); RD_B(BBUF0, sw1);
    stage_half(A, m0 + 128, lds + ABUF1 + 8192, tid, k1);
    PBAR(); LGKM0(); DO_MFMA(0); PBAR();
    // ph4: buf0 (M1,ks1); stage (2i+2).Bh1 (BBUF0.B last read ph3);
    // vmcnt(2): only ph4's own stage outstanding -> tile 2i+1 fully resident.
    RD_A(ABUF0, 1, sw1);
    stage_half(B, n0, lds + BBUF0, tid, k2);
    VM2();
    PBAR(); LGKM0(); DO_MFMA(1); PBAR();
    // ph5: buf1 (M0,ks0); stage (2i+2).Bh2
    RD_A(ABUF1, 0, sw0); RD_B(BBUF1, sw0);
    stage_half(B, n0 + 128, lds + BBUF0 + 8192, tid, k2);
    PBAR(); LGKM0(); DO_MFMA(0); PBAR();
    // ph6: buf1 (M1,ks0); stage (2i+2).Ah1 (ABUF0 last read ph4)
    RD_A(ABUF1, 1, sw0);
    stage_half(A, m0, lds + ABUF0, tid, k2);
    PBAR(); LGKM0(); DO_MFMA(1); PBAR();
    // ph7: buf1 (M0,ks1); stage (2i+2).Ah2
    RD_A(ABUF1, 0, sw1); RD_B(BBUF1, sw1);
    stage_half(A, m0 + 128, lds + ABUF0 + 8192, tid, k2);
    PBAR(); LGKM0(); DO_MFMA(0); PBAR();
    // ph8: buf1 (M1,ks1); stage (2i+3).Bh1 (BBUF1.B last read ph7);
    // vmcnt(2) -> tile 2i+2 fully resident for next ph1.
    RD_A(ABUF1, 1, sw1);
    stage_half(B, n0, lds + BBUF1, tid, k3);
    VM2();
    PBAR(); LGKM0(); DO_MFMA(1); PBAR();
  }

  // Epilogue: C/D layout col=lane&15, row=(lane>>4)*4+reg
#pragma unroll
  for (int m = 0; m < 8; ++m)
#pragma unroll
    for (int nf = 0; nf < 4; ++nf)
#pragma unroll
      for (int r = 0; r < 4; ++r) {
        int row = m0 + wr * 128 + m * 16 + (l >> 4) * 4 + r;
        int col = n0 + wc * 64 + nf * 16 + (l & 15);
        if (OUTBF)
          ((unsigned short*)Cv)[(size_t)row * (NTN * 256) + col] = f2bf(acc[m][nf][r]);
        else
          ((float*)Cv)[(size_t)row * (NTN * 256) + col] = acc[m][nf][r];
      }
}

// ---------------- attention: per (b,h) wave ----------------
#define QOFF 0
#define KOFF 1152
#define VOFF 2304
#define SOFF 3328
__global__ __launch_bounds__(256) void attn_k(const unsigned short* __restrict__ qkv,
                                              unsigned short* __restrict__ attn) {
  __shared__ __align__(16) unsigned short lds[4 * 3584];
  int tid = threadIdx.x, wid = tid >> 6, l = tid & 63;
  int p = blockIdx.x * 4 + wid;
  int b = p >> 3, h = p & 7;
  unsigned short* W = &lds[wid * 3584];
  const size_t rowb = (size_t)(b * 16) * 1536;

  float kv[16];
#pragma unroll
  for (int n = 0; n < 16; ++n) kv[n] = bf2f(qkv[rowb + n * 1536 + 512 + h * 64 + l]);
  float km = kv[0];
#pragma unroll
  for (int n = 1; n < 16; ++n) km = fmaxf(km, kv[n]);
  float ks = 0.f;
#pragma unroll
  for (int n = 0; n < 16; ++n) { kv[n] = __expf(kv[n] - km); ks += kv[n]; }
  float kinv = 1.f / ks;
#pragma unroll
  for (int n = 0; n < 16; ++n) W[KOFF + n * 72 + l] = f2bf(kv[n] * kinv);

#pragma unroll
  for (int n = 0; n < 16; ++n) {
    float x = bf2f(qkv[rowb + n * 1536 + h * 64 + l]);
    float mx = x;
    mx = fmaxf(mx, __shfl_xor(mx, 1));  mx = fmaxf(mx, __shfl_xor(mx, 2));
    mx = fmaxf(mx, __shfl_xor(mx, 4));  mx = fmaxf(mx, __shfl_xor(mx, 8));
    mx = fmaxf(mx, __shfl_xor(mx, 16)); mx = fmaxf(mx, __shfl_xor(mx, 32));
    float e = __expf(x - mx);
    float s = e;
    s += __shfl_xor(s, 1);  s += __shfl_xor(s, 2);  s += __shfl_xor(s, 4);
    s += __shfl_xor(s, 8);  s += __shfl_xor(s, 16); s += __shfl_xor(s, 32);
    W[QOFF + n * 72 + l] = f2bf(e / s * 0.125f);
  }

  const unsigned short* vp = qkv + rowb + (size_t)(l >> 2) * 1536 + 1024 + h * 64 + (l & 3) * 16;
  bf16x8 v0 = *(const bf16x8*)vp;
  bf16x8 v1 = *(const bf16x8*)(vp + 8);
#pragma unroll
  for (int c = 0; c < 8; ++c)
    W[VOFF + ((l & 3) * 16 + c) * 16 + (l >> 2)] = (unsigned short)v0[c];
#pragma unroll
  for (int c = 0; c < 8; ++c)
    W[VOFF + ((l & 3) * 16 + 8 + c) * 16 + (l >> 2)] = (unsigned short)v1[c];
  __syncthreads();

  f32x4 sacc = {0.f, 0.f, 0.f, 0.f};
#pragma unroll
  for (int kb = 0; kb < 2; ++kb) {
    bf16x8 a  = *(const bf16x8*)&W[QOFF + (l & 15) * 72 + kb * 32 + (l >> 4) * 8];
    bf16x8 bb = *(const bf16x8*)&W[KOFF + (l & 15) * 72 + kb * 32 + (l >> 4) * 8];
    sacc = __builtin_amdgcn_mfma_f32_16x16x32_bf16(a, bb, sacc, 0, 0, 0);
  }
#pragma unroll
  for (int r = 0; r < 4; ++r)
    W[SOFF + ((l >> 4) * 4 + r) * 16 + (l & 15)] = f2bf(sacc[r]);
  __syncthreads();

  bf16x8 zz = {0, 0, 0, 0, 0, 0, 0, 0};
  bf16x8 sa = zz;
  if (l < 32) sa = *(const bf16x8*)&W[SOFF + (l & 15) * 16 + (l >> 4) * 8];
#pragma unroll
  for (int et = 0; et < 4; ++et) {
    bf16x8 vb = zz;
    if (l < 32) vb = *(const bf16x8*)&W[VOFF + (et * 16 + (l & 15)) * 16 + (l >> 4) * 8];
    f32x4 o = {0.f, 0.f, 0.f, 0.f};
    o = __builtin_amdgcn_mfma_f32_16x16x32_bf16(sa, vb, o, 0, 0, 0);
#pragma unroll
    for (int r = 0; r < 4; ++r)
      attn[(size_t)(b * 16 + (l >> 4) * 4 + r) * 512 + h * 64 + et * 16 + (l & 15)] = f2bf(o[r]);
  }
}

extern "C" void kernel_launch(void* const* d_in, const int* in_sizes, int n_in,
                              void* d_out, int out_size, void* d_ws, size_t ws_size,
                              hipStream_t stream) {
  const float* x  = (const float*)d_in[0];   // [4096,16,512]
  const float* wq = (const float*)d_in[1];   // [512,1536]
  const float* wo = (const float*)d_in[2];   // [512,512]
  float* out = (float*)d_out;                // [4096,16,512] f32

  unsigned short* xb   = (unsigned short*)d_ws;
  unsigned short* wqt  = xb  + 33554432;   // 65536*512
  unsigned short* wot  = wqt + 786432;     // 1536*512
  unsigned short* qkv  = wot + 262144;     // 512*512
  unsigned short* attn = xb;               // alias: xb dead after gemm_qkv

  conv_x_k<<<16384, 256, 0, stream>>>(x, xb);
  conv_w_k<<<4096,  256, 0, stream>>>(wq, wo, wqt, wot);
  gemm8_k<6, true><<<1536, 512, 0, stream>>>(xb, wqt, qkv);
  attn_k<<<8192, 256, 0, stream>>>(qkv, attn);
  gemm8_k<2, false><<<512, 512, 0, stream>>>(attn, wot, out);
}

// Round 5
// 507.337 us; speedup vs baseline: 1.0098x; 1.0098x over previous
//
#include <hip/hip_runtime.h>
#include <hip/hip_bf16.h>

// TemporalLinearAttention: out = ((softmax_d(q)*s) @ k_sm^T @ v) @ w_out
// qkv = x @ w_qkv, reassociated (q@k^T)@v.
// Pipeline: conv_x, conv_w -> gemm8<6,bf16> (qkv) -> attn -> gemm8<2,f32> (out)
//
// gemm8 r4: 256x256, BK=64, 8 waves, 8-phase. No manual lgkmcnt (compiler
// schedules ds_read->MFMA fine-grained). Stages: ph1/ph2 (odd tile A),
// ph4x2 (even B), ph5/ph6 (even A), ph8x2 (odd B); vmcnt(4) after MFMA at
// ph4/ph8 only. MFMA operands SWAPPED -> lane holds 4 consecutive C-cols:
// coalesced 8B/16B epilogue stores.

typedef __attribute__((ext_vector_type(8))) short bf16x8;
typedef __attribute__((ext_vector_type(4))) float f32x4;

__device__ __forceinline__ unsigned short f2bf(float f) {
  __hip_bfloat16 h = __float2bfloat16(f);
  return __builtin_bit_cast(unsigned short, h);
}
__device__ __forceinline__ float bf2f(unsigned short u) {
  unsigned int v = ((unsigned int)u) << 16;
  return __builtin_bit_cast(float, v);
}
__device__ __forceinline__ void gload16(const void* g, void* l) {
  __builtin_amdgcn_global_load_lds(
      (__attribute__((address_space(1))) void*)g,
      (__attribute__((address_space(3))) void*)l, 16, 0, 0);
}

// ---------------- conversions ----------------
__global__ __launch_bounds__(256) void conv_x_k(const float* __restrict__ x,
                                                unsigned short* __restrict__ xb) {
  size_t i = ((size_t)blockIdx.x * 256 + threadIdx.x) * 8;
  float4 a = *(const float4*)(x + i);
  float4 b = *(const float4*)(x + i + 4);
  union { unsigned short u[8]; bf16x8 v; } o;
  o.u[0] = f2bf(a.x); o.u[1] = f2bf(a.y); o.u[2] = f2bf(a.z); o.u[3] = f2bf(a.w);
  o.u[4] = f2bf(b.x); o.u[5] = f2bf(b.y); o.u[6] = f2bf(b.z); o.u[7] = f2bf(b.w);
  *(bf16x8*)(xb + i) = o.v;
}

__global__ __launch_bounds__(256) void conv_w_k(const float* __restrict__ wq,
                                                const float* __restrict__ wo,
                                                unsigned short* __restrict__ wqt,
                                                unsigned short* __restrict__ wot) {
  int i = blockIdx.x * 256 + threadIdx.x;
  if (i < 786432) {
    int n = i >> 9, k = i & 511;
    wqt[i] = f2bf(wq[k * 1536 + n]);
  } else {
    int j = i - 786432;
    int n = j >> 9, k = j & 511;
    wot[j] = f2bf(wo[k * 512 + n]);
  }
}

// ---------------- 8-phase 256x256 GEMM (K=512 fixed) ----------------
#define ABUF0 0
#define ABUF1 16384
#define BBUF0 32768
#define BBUF1 49152

__device__ __forceinline__ void stage_half(const unsigned short* __restrict__ G,
                                           int grow0, unsigned short* ldsb,
                                           int tid, int kofs) {
  int r = tid >> 3;                      // row within half (0..63), +64 for 2nd
  int c = ((tid & 7) ^ (r & 7)) << 3;    // inverse-swizzled logical k-chunk
  gload16(G + (size_t)(grow0 + r) * 512 + kofs + c, ldsb + tid * 8);
  gload16(G + (size_t)(grow0 + 64 + r) * 512 + kofs + c, ldsb + 4096 + tid * 8);
}

#define RD_A(base, mh, sw)                                                   \
  _Pragma("unroll") for (int mf = 0; mf < 4; ++mf)                           \
      aF[mf] = *(const bf16x8*)&lds[(base) + (rowA + (mh)*64 + mf*16) * 64 + (sw)];
#define RD_B(base, sw)                                                       \
  _Pragma("unroll") for (int nf = 0; nf < 4; ++nf)                           \
      bF[nf] = *(const bf16x8*)&lds[(base) + (rowB + nf*16) * 64 + (sw)];
// SWAPPED operands: acc = C^T fragments -> lane l holds row (l&15),
// cols (l>>4)*4 + r (4 consecutive) of the wave's sub-tile.
#define DO_MFMA(mh)                                                          \
  __builtin_amdgcn_s_setprio(1);                                             \
  _Pragma("unroll") for (int mf = 0; mf < 4; ++mf)                           \
  _Pragma("unroll") for (int nf = 0; nf < 4; ++nf)                           \
      acc[(mh)*4 + mf][nf] = __builtin_amdgcn_mfma_f32_16x16x32_bf16(        \
          bF[nf], aF[mf], acc[(mh)*4 + mf][nf], 0, 0, 0);                    \
  __builtin_amdgcn_s_setprio(0);
#define PBAR() __builtin_amdgcn_s_barrier()
#define VM4() asm volatile("s_waitcnt vmcnt(4)" ::: "memory")

template <int NTN, bool OUTBF>
__global__ __launch_bounds__(512) void gemm8_k(const unsigned short* __restrict__ A,
                                               const unsigned short* __restrict__ B,
                                               void* __restrict__ Cv) {
  __shared__ __align__(16) unsigned short lds[65536];  // 128 KiB
  int orig = blockIdx.x;
  int id = (orig & 7) * (gridDim.x >> 3) + (orig >> 3);  // XCD-chunked (grid%8==0)
  int mt = id / NTN, nt = id % NTN;
  int m0 = mt * 256, n0 = nt * 256;
  int tid = threadIdx.x, wid = tid >> 6, l = tid & 63;
  int wr = wid >> 2, wc = wid & 3;          // 2M x 4N waves; wave owns 128x64
  int rowA = wr * 128 + (l & 15);
  int rowB = wc * 64 + (l & 15);
  int r7 = l & 7;
  int sw0 = ((l >> 4) ^ r7) << 3;
  int sw1 = (((l >> 4) | 4) ^ r7) << 3;

  f32x4 acc[8][4];
#pragma unroll
  for (int i = 0; i < 8; ++i)
#pragma unroll
    for (int j = 0; j < 4; ++j) acc[i][j] = (f32x4){0.f, 0.f, 0.f, 0.f};
  bf16x8 aF[4], bF[4];

  // Prologue: T0 all 4 halves + T1 both B halves; vmcnt(4) -> T0 resident.
  stage_half(B, n0,       lds + BBUF0,        tid, 0);
  stage_half(B, n0 + 128, lds + BBUF0 + 8192, tid, 0);
  stage_half(A, m0,       lds + ABUF0,        tid, 0);
  stage_half(A, m0 + 128, lds + ABUF0 + 8192, tid, 0);
  stage_half(B, n0,       lds + BBUF1,        tid, 64);
  stage_half(B, n0 + 128, lds + BBUF1 + 8192, tid, 64);
  VM4();
  PBAR();

  for (int it = 0; it < 4; ++it) {
    int k1 = (2 * it + 1) * 64;                 // odd tile (<=7, always real)
    int t2 = 2 * it + 2; if (t2 > 7) t2 = 7;    // tail stages land in dead regions
    int t3 = 2 * it + 3; if (t3 > 7) t3 = 7;
    int k2 = t2 * 64, k3 = t3 * 64;

    // ph1: read buf0(M0,ks0); stage T1.Ah1 (ABUF1 free since prev ph8)
    RD_A(ABUF0, 0, sw0); RD_B(BBUF0, sw0);
    stage_half(A, m0, lds + ABUF1, tid, k1);
    PBAR(); DO_MFMA(0); PBAR();
    // ph2: stage T1.Ah2
    RD_A(ABUF0, 1, sw0);
    stage_half(A, m0 + 128, lds + ABUF1 + 8192, tid, k1);
    PBAR(); DO_MFMA(1); PBAR();
    // ph3: no stage
    RD_A(ABUF0, 0, sw1); RD_B(BBUF0, sw1);
    PBAR(); DO_MFMA(0); PBAR();
    // ph4: stage T2.Bh1+Bh2 (BBUF0.B last read ph3); vmcnt(4) after MFMA ->
    // T1 fully resident before the end barrier publishes buf1.
    RD_A(ABUF0, 1, sw1);
    stage_half(B, n0,       lds + BBUF0,        tid, k2);
    stage_half(B, n0 + 128, lds + BBUF0 + 8192, tid, k2);
    PBAR(); DO_MFMA(1); VM4(); PBAR();
    // ph5: read buf1(M0,ks0); stage T2.Ah1 (ABUF0 free after ph4)
    RD_A(ABUF1, 0, sw0); RD_B(BBUF1, sw0);
    stage_half(A, m0, lds + ABUF0, tid, k2);
    PBAR(); DO_MFMA(0); PBAR();
    // ph6: stage T2.Ah2
    RD_A(ABUF1, 1, sw0);
    stage_half(A, m0 + 128, lds + ABUF0 + 8192, tid, k2);
    PBAR(); DO_MFMA(1); PBAR();
    // ph7: no stage
    RD_A(ABUF1, 0, sw1); RD_B(BBUF1, sw1);
    PBAR(); DO_MFMA(0); PBAR();
    // ph8: stage T3.Bh1+Bh2 (BBUF1.B last read ph7); vmcnt(4) -> T2 resident.
    RD_A(ABUF1, 1, sw1);
    stage_half(B, n0,       lds + BBUF1,        tid, k3);
    stage_half(B, n0 + 128, lds + BBUF1 + 8192, tid, k3);
    PBAR(); DO_MFMA(1); VM4(); PBAR();
  }

  // Epilogue: acc = C^T frags. Lane l: row = base + (l&15), 4 consecutive
  // cols = n-base + (l>>4)*4. 8B (bf16) / 16B (f32) stores.
#pragma unroll
  for (int m = 0; m < 8; ++m)
#pragma unroll
    for (int n = 0; n < 4; ++n) {
      int row = m0 + wr * 128 + m * 16 + (l & 15);
      int col = n0 + wc * 64 + n * 16 + (l >> 4) * 4;
      if (OUTBF) {
        unsigned int lo = (unsigned int)f2bf(acc[m][n][0]) |
                          ((unsigned int)f2bf(acc[m][n][1]) << 16);
        unsigned int hi = (unsigned int)f2bf(acc[m][n][2]) |
                          ((unsigned int)f2bf(acc[m][n][3]) << 16);
        uint2 pk = {lo, hi};
        *(uint2*)((unsigned short*)Cv + (size_t)row * (NTN * 256) + col) = pk;
      } else {
        *(f32x4*)((float*)Cv + (size_t)row * (NTN * 256) + col) = acc[m][n];
      }
    }
}

// ---------------- attention: per (b,h) wave ----------------
#define QOFF 0
#define KOFF 1152
#define VOFF 2304
#define SOFF 3328
__global__ __launch_bounds__(256) void attn_k(const unsigned short* __restrict__ qkv,
                                              unsigned short* __restrict__ attn) {
  __shared__ __align__(16) unsigned short lds[4 * 3584];
  int tid = threadIdx.x, wid = tid >> 6, l = tid & 63;
  int p = blockIdx.x * 4 + wid;
  int b = p >> 3, h = p & 7;
  unsigned short* W = &lds[wid * 3584];
  const size_t rowb = (size_t)(b * 16) * 1536;

  float kv[16];
#pragma unroll
  for (int n = 0; n < 16; ++n) kv[n] = bf2f(qkv[rowb + n * 1536 + 512 + h * 64 + l]);
  float km = kv[0];
#pragma unroll
  for (int n = 1; n < 16; ++n) km = fmaxf(km, kv[n]);
  float ks = 0.f;
#pragma unroll
  for (int n = 0; n < 16; ++n) { kv[n] = __expf(kv[n] - km); ks += kv[n]; }
  float kinv = 1.f / ks;
#pragma unroll
  for (int n = 0; n < 16; ++n) W[KOFF + n * 72 + l] = f2bf(kv[n] * kinv);

#pragma unroll
  for (int n = 0; n < 16; ++n) {
    float x = bf2f(qkv[rowb + n * 1536 + h * 64 + l]);
    float mx = x;
    mx = fmaxf(mx, __shfl_xor(mx, 1));  mx = fmaxf(mx, __shfl_xor(mx, 2));
    mx = fmaxf(mx, __shfl_xor(mx, 4));  mx = fmaxf(mx, __shfl_xor(mx, 8));
    mx = fmaxf(mx, __shfl_xor(mx, 16)); mx = fmaxf(mx, __shfl_xor(mx, 32));
    float e = __expf(x - mx);
    float s = e;
    s += __shfl_xor(s, 1);  s += __shfl_xor(s, 2);  s += __shfl_xor(s, 4);
    s += __shfl_xor(s, 8);  s += __shfl_xor(s, 16); s += __shfl_xor(s, 32);
    W[QOFF + n * 72 + l] = f2bf(e / s * 0.125f);
  }

  const unsigned short* vp = qkv + rowb + (size_t)(l >> 2) * 1536 + 1024 + h * 64 + (l & 3) * 16;
  bf16x8 v0 = *(const bf16x8*)vp;
  bf16x8 v1 = *(const bf16x8*)(vp + 8);
#pragma unroll
  for (int c = 0; c < 8; ++c)
    W[VOFF + ((l & 3) * 16 + c) * 16 + (l >> 2)] = (unsigned short)v0[c];
#pragma unroll
  for (int c = 0; c < 8; ++c)
    W[VOFF + ((l & 3) * 16 + 8 + c) * 16 + (l >> 2)] = (unsigned short)v1[c];
  __syncthreads();

  f32x4 sacc = {0.f, 0.f, 0.f, 0.f};
#pragma unroll
  for (int kb = 0; kb < 2; ++kb) {
    bf16x8 a  = *(const bf16x8*)&W[QOFF + (l & 15) * 72 + kb * 32 + (l >> 4) * 8];
    bf16x8 bb = *(const bf16x8*)&W[KOFF + (l & 15) * 72 + kb * 32 + (l >> 4) * 8];
    sacc = __builtin_amdgcn_mfma_f32_16x16x32_bf16(a, bb, sacc, 0, 0, 0);
  }
#pragma unroll
  for (int r = 0; r < 4; ++r)
    W[SOFF + ((l >> 4) * 4 + r) * 16 + (l & 15)] = f2bf(sacc[r]);
  __syncthreads();

  bf16x8 zz = {0, 0, 0, 0, 0, 0, 0, 0};
  bf16x8 sa = zz;
  if (l < 32) sa = *(const bf16x8*)&W[SOFF + (l & 15) * 16 + (l >> 4) * 8];
#pragma unroll
  for (int et = 0; et < 4; ++et) {
    bf16x8 vb = zz;
    if (l < 32) vb = *(const bf16x8*)&W[VOFF + (et * 16 + (l & 15)) * 16 + (l >> 4) * 8];
    f32x4 o = {0.f, 0.f, 0.f, 0.f};
    o = __builtin_amdgcn_mfma_f32_16x16x32_bf16(sa, vb, o, 0, 0, 0);
#pragma unroll
    for (int r = 0; r < 4; ++r)
      attn[(size_t)(b * 16 + (l >> 4) * 4 + r) * 512 + h * 64 + et * 16 + (l & 15)] = f2bf(o[r]);
  }
}

extern "C" void kernel_launch(void* const* d_in, const int* in_sizes, int n_in,
                              void* d_out, int out_size, void* d_ws, size_t ws_size,
                              hipStream_t stream) {
  const float* x  = (const float*)d_in[0];   // [4096,16,512]
  const float* wq = (const float*)d_in[1];   // [512,1536]
  const float* wo = (const float*)d_in[2];   // [512,512]
  float* out = (float*)d_out;                // [4096,16,512] f32

  unsigned short* xb   = (unsigned short*)d_ws;
  unsigned short* wqt  = xb  + 33554432;   // 65536*512
  unsigned short* wot  = wqt + 786432;     // 1536*512
  unsigned short* qkv  = wot + 262144;     // 512*512
  unsigned short* attn = xb;               // alias: xb dead after gemm_qkv

  conv_x_k<<<16384, 256, 0, stream>>>(x, xb);
  conv_w_k<<<4096,  256, 0, stream>>>(wq, wo, wqt, wot);
  gemm8_k<6, true><<<1536, 512, 0, stream>>>(xb, wqt, qkv);
  attn_k<<<8192, 256, 0, stream>>>(qkv, attn);
  gemm8_k<2, false><<<512, 512, 0, stream>>>(attn, wot, out);
}